// Round 4
// baseline (840.535 us; speedup 1.0000x reference)
//
#include <hip/hip_runtime.h>
#include <math.h>

#define N_ROWS 50000
#define DIM 512
#define NPAD 50048          // 391 * 128, padded row count for OOB-safe global_load_lds

// K2 tile
#define BM 128
#define BN 128
#define BK 32
#define N_STRIPS 391        // ceil(50000/128)
#define STRIPS_PER_XCD 49   // ceil(391/8)
#define N_COLS 4            // 512 / BN

typedef __attribute__((ext_vector_type(8))) short short8;
typedef __attribute__((ext_vector_type(4))) float float4v;

__device__ inline unsigned short f2bf(float x) {
    union { float f; unsigned u; } v; v.f = x;
    unsigned r = v.u + 0x7fffu + ((v.u >> 16) & 1u);  // RNE
    return (unsigned short)(r >> 16);
}

__device__ inline float bf2f(unsigned short u) {
    union { unsigned u; float f; } v; v.u = ((unsigned)u) << 16; return v.f;
}

__device__ inline short8 packv(float4v x, float4v y) {
    short8 r;
    r[0] = (short)f2bf(x[0]); r[1] = (short)f2bf(x[1]);
    r[2] = (short)f2bf(x[2]); r[3] = (short)f2bf(x[3]);
    r[4] = (short)f2bf(y[0]); r[5] = (short)f2bf(y[1]);
    r[6] = (short)f2bf(y[2]); r[7] = (short)f2bf(y[3]);
    return r;
}

// tanh via hw exp + rcp: ~7 VALU ops vs ~20+ for ocml tanhf.
__device__ inline float fast_tanh(float x) {
    float xc = fminf(fmaxf(x, -15.f), 15.f);
    float e = __expf(2.0f * xc);
    return 1.0f - 2.0f * __builtin_amdgcn_rcpf(e + 1.0f);
}

__device__ inline void async_ld16(const void* g, void* l) {
    __builtin_amdgcn_global_load_lds(
        (__attribute__((address_space(1))) void*)g,
        (__attribute__((address_space(3))) void*)l, 16, 0, 0);
}

// ---- K1: one streaming pass: fp32->bf16 embeddings (+shared), W mats, sums=0 ----
// 16 elems/thread (coarsened: probe whether the ~258us residual is convert work
// or fixed overhead).
#define EMBED_BLOCKS 6256    // NPAD*512/16/256
#define W_BLOCKS 192         // 3*512*512/16/256
__global__ __launch_bounds__(256) void convert_all(
    const float* __restrict__ img, const float* __restrict__ ph,
    const float* __restrict__ Wi, const float* __restrict__ Wp, const float* __restrict__ Ws,
    unsigned short* __restrict__ img_bf, unsigned short* __restrict__ ph_bf,
    unsigned short* __restrict__ sh_bf,
    unsigned short* __restrict__ Wi_bf, unsigned short* __restrict__ Wp_bf,
    unsigned short* __restrict__ Ws_bf,
    float* __restrict__ sums)
{
    const int bid = blockIdx.x;
    if (bid == 0 && threadIdx.x < 3) sums[threadIdx.x] = 0.0f;

    if (bid < EMBED_BLOCKS) {
        const size_t idx = ((size_t)bid * 256 + threadIdx.x) * 16;
        const int row = (int)(idx >> 9);   // 16 elems stay within one 512-row
        if (row < N_ROWS) {
#pragma unroll
            for (int h = 0; h < 2; ++h) {
                const size_t o = idx + h * 8;
                float4v i0 = *(const float4v*)(img + o);
                float4v i1 = *(const float4v*)(img + o + 4);
                float4v p0 = *(const float4v*)(ph + o);
                float4v p1 = *(const float4v*)(ph + o + 4);
                *(short8*)(img_bf + o) = packv(i0, i1);
                *(short8*)(ph_bf + o)  = packv(p0, p1);
                *(short8*)(sh_bf + o)  = packv(0.5f * (i0 + p0), 0.5f * (i1 + p1));
            }
        } else {
            short8 z = (short8){0,0,0,0,0,0,0,0};
#pragma unroll
            for (int h = 0; h < 2; ++h) {
                const size_t o = idx + h * 8;
                *(short8*)(img_bf + o) = z;
                *(short8*)(ph_bf + o)  = z;
                *(short8*)(sh_bf + o)  = z;
            }
        }
    } else {
        const int t = (bid - EMBED_BLOCKS) * 256 + threadIdx.x;  // 0..49151
        const int mat = t >> 14;                                 // 16384 threads/matrix
        const size_t idx = (size_t)(t & 16383) * 16;
        const float* src = (mat == 0) ? Wi : ((mat == 1) ? Wp : Ws);
        unsigned short* dst = (mat == 0) ? Wi_bf : ((mat == 1) ? Wp_bf : Ws_bf);
#pragma unroll
        for (int h = 0; h < 2; ++h) {
            const size_t o = idx + h * 8;
            *(short8*)(dst + o) = packv(*(const float4v*)(src + o),
                                        *(const float4v*)(src + o + 4));
        }
    }
}

// ---- K2: fused triple GEMM + tanh + joint combine + Frobenius sums ----
// 512 threads / 8 waves, 128x128 tile. Staged bytes per wave-MFMA = 250 B
// (m97's ratio); 6 DMA chunks/wave/iter (was 9 for half the output).
// XCD swizzle kept from round 3 (FETCH_SIZE went 690->138 MB with it).
__global__ __launch_bounds__(512, 2) void fused_mma2(
    const unsigned short* __restrict__ img_bf, const unsigned short* __restrict__ ph_bf,
    const unsigned short* __restrict__ sh_bf,
    const unsigned short* __restrict__ Wi_bf, const unsigned short* __restrict__ Wp_bf,
    const unsigned short* __restrict__ Ws_bf,
    const float* __restrict__ bs, const float* __restrict__ bi, const float* __restrict__ bp,
    float* __restrict__ out, float* __restrict__ sums)
{
    const int bid  = blockIdx.x;
    const int xcd  = bid & 7;
    const int u    = bid >> 3;
    const int col  = u & 3;             // col-tile fastest within XCD slab
    const int s    = u >> 2;            // 0..48
    const int strip = xcd * STRIPS_PER_XCD + s;
    if (strip >= N_STRIPS) return;

    const int e0 = col * BN;
    const int n0 = strip * BM;

    // unpadded: global_load_lds writes wave-uniform base + lane*16
    __shared__ __align__(16) unsigned short sA[3][BM][BK];  // 24 KB
    __shared__ __align__(16) unsigned short sB[3][BN][BK];  // 24 KB

    const int tid  = threadIdx.x;
    const int lane = tid & 63;
    const int wid  = tid >> 6;          // 0..7
    const int wm   = wid & 1;           // 64-row half
    const int wn   = wid >> 1;          // 32-col quarter (0..3)
    const int l15  = lane & 15;
    const int quad = lane >> 4;

    const unsigned short* Amat[3] = { img_bf, ph_bf, sh_bf };
    const unsigned short* Bmat[3] = { Wi_bf, Wp_bf, Ws_bf };

    const int lrow = lane >> 2;         // 0..15
    const int lcol = (lane & 3) * 8;    // 0,8,16,24

    float4v acc[3][4][2];
#pragma unroll
    for (int m = 0; m < 3; ++m)
#pragma unroll
        for (int i = 0; i < 4; ++i)
#pragma unroll
            for (int j = 0; j < 2; ++j)
                acc[m][i][j] = (float4v){0.f, 0.f, 0.f, 0.f};

#pragma unroll 1
    for (int kb = 0; kb < DIM / BK; ++kb) {
        const int k0 = kb * BK;

        // 48 chunks of 1 KB (24 A: 3 mats x 8 row-subtiles; 24 B likewise),
        // 6 per wave.
#pragma unroll
        for (int t = 0; t < 6; ++t) {
            const int c = wid * 6 + t;
            if (c < 24) {
                const int mat = c >> 3, sub = c & 7;
                const unsigned short* g =
                    Amat[mat] + (size_t)(n0 + sub * 16 + lrow) * DIM + k0 + lcol;
                async_ld16(g, &sA[mat][sub * 16][0]);
            } else {
                const int cc = c - 24;
                const int mat = cc >> 3, sub = cc & 7;
                const unsigned short* g =
                    Bmat[mat] + (size_t)(e0 + sub * 16 + lrow) * DIM + k0 + lcol;
                async_ld16(g, &sB[mat][sub * 16][0]);
            }
        }

        __syncthreads();

#pragma unroll
        for (int mat = 0; mat < 3; ++mat) {
            short8 a[4], b[2];
#pragma unroll
            for (int i = 0; i < 4; ++i)
                a[i] = *(const short8*)&sA[mat][wm * 64 + i * 16 + l15][quad * 8];
#pragma unroll
            for (int j = 0; j < 2; ++j)
                b[j] = *(const short8*)&sB[mat][wn * 32 + j * 16 + l15][quad * 8];
#pragma unroll
            for (int i = 0; i < 4; ++i)
#pragma unroll
                for (int j = 0; j < 2; ++j)
                    acc[mat][i][j] = __builtin_amdgcn_mfma_f32_16x16x32_bf16(
                        a[i], b[j], acc[mat][i][j], 0, 0, 0);
        }

        __syncthreads();
    }

    // ---- epilogue ----
    float s_i = 0.f, s_p = 0.f, s_s = 0.f;
#pragma unroll
    for (int i = 0; i < 4; ++i) {
#pragma unroll
        for (int j = 0; j < 2; ++j) {
            const int c = e0 + wn * 32 + j * 16 + l15;
            const float bii = bi[c], bpp = bp[c], bss = bs[c];
            const int rbase = n0 + wm * 64 + i * 16 + quad * 4;
#pragma unroll
            for (int r = 0; r < 4; ++r) {
                const int nrow = rbase + r;
                const float ia = fast_tanh(acc[0][i][j][r] + bii);
                const float pa = fast_tanh(acc[1][i][j][r] + bpp);
                const float sa = fast_tanh(acc[2][i][j][r] + bss);
                if (nrow < N_ROWS) {
                    const size_t off = (size_t)nrow * DIM + c;
                    const float ie = bf2f(img_bf[off]);
                    const float pe = bf2f(ph_bf[off]);
                    const float se = 0.5f * (ie + pe);
                    out[off] = sa * se + ia * ie + pa * pe;
                    s_i += ia * ia; s_p += pa * pa; s_s += sa * sa;
                }
            }
        }
    }

#pragma unroll
    for (int off = 32; off > 0; off >>= 1) {
        s_i += __shfl_down(s_i, off);
        s_p += __shfl_down(s_p, off);
        s_s += __shfl_down(s_s, off);
    }
    if (lane == 0) {
        atomicAdd(&sums[0], s_i);
        atomicAdd(&sums[1], s_p);
        atomicAdd(&sums[2], s_s);
    }
}

__global__ void finalize(const float* __restrict__ sums, float* __restrict__ wout) {
    if (threadIdx.x == 0) {
        const float inv_sh = 1.0f / sums[2];
        const float is = sums[0] * inv_sh;
        const float ps = sums[1] * inv_sh;
        const float m  = fmaxf(is, ps);
        const float ei = expf(is - m), ep = expf(ps - m);
        const float inv = 1.0f / (ei + ep);
        wout[0] = ei * inv;
        wout[1] = ep * inv;
    }
}

extern "C" void kernel_launch(void* const* d_in, const int* in_sizes, int n_in,
                              void* d_out, int out_size, void* d_ws, size_t ws_size,
                              hipStream_t stream) {
    const float* img = (const float*)d_in[0];
    const float* ph  = (const float*)d_in[1];
    const float* Ws  = (const float*)d_in[2];
    const float* bs  = (const float*)d_in[3];
    const float* Wi  = (const float*)d_in[4];
    const float* bi  = (const float*)d_in[5];
    const float* Wp  = (const float*)d_in[6];
    const float* bp  = (const float*)d_in[7];
    float* out  = (float*)d_out;
    float* sums = (float*)d_ws;

    const size_t embed_elems = (size_t)NPAD * DIM;
    const size_t w_elems = (size_t)DIM * DIM;

    unsigned short* base   = (unsigned short*)((char*)d_ws + 256);
    unsigned short* img_bf = base;
    unsigned short* ph_bf  = img_bf + embed_elems;
    unsigned short* sh_bf  = ph_bf + embed_elems;
    unsigned short* Wi_bf  = sh_bf + embed_elems;
    unsigned short* Wp_bf  = Wi_bf + w_elems;
    unsigned short* Ws_bf  = Wp_bf + w_elems;

    convert_all<<<EMBED_BLOCKS + W_BLOCKS, 256, 0, stream>>>(
        img, ph, Wi, Wp, Ws, img_bf, ph_bf, sh_bf, Wi_bf, Wp_bf, Ws_bf, sums);

    // 8 xcds x 49 strips x 4 cols = 1568 blocks (4 no-ops where strip >= 391)
    fused_mma2<<<8 * STRIPS_PER_XCD * N_COLS, 512, 0, stream>>>(
        img_bf, ph_bf, sh_bf, Wi_bf, Wp_bf, Ws_bf, bs, bi, bp, out, sums);

    finalize<<<1, 64, 0, stream>>>(sums, out + (size_t)N_ROWS * DIM);
}